// Round 6
// baseline (195.673 us; speedup 1.0000x reference)
//
#include <hip/hip_runtime.h>
#include <stdint.h>

#define H_HEADS 8
#define DDIM 64
#define NNODES 8192
#define BB 2
#define FIN 512
#define FOUT 512
#define EDGES 65536
#define CAP 32   // per-node edge bucket capacity (Poisson λ=8; P(deg>=32)~1e-11)
#define NEBLK 64 // edge-build blocks fused into gemm grid (run first)

typedef unsigned short u16;
typedef unsigned int u32;
typedef __bf16 bf16x8 __attribute__((ext_vector_type(8)));
typedef float f32x4 __attribute__((ext_vector_type(4)));

__device__ __forceinline__ u16 f2bf(float f) {
    u32 u = __float_as_uint(f);
    return (u16)((u + 0x7FFFu + ((u >> 16) & 1u)) >> 16);
}
__device__ __forceinline__ float bf2f(u32 s) {
    return __uint_as_float(s << 16);
}
__device__ __forceinline__ uint4 pack8(float4 a, float4 b) {
    return make_uint4(f2bf(a.x) | ((u32)f2bf(a.y) << 16),
                      f2bf(a.z) | ((u32)f2bf(a.w) << 16),
                      f2bf(b.x) | ((u32)f2bf(b.y) << 16),
                      f2bf(b.z) | ((u32)f2bf(b.w) << 16));
}

// ---------------- prep: cast W -> bf16 (tiny) -------------------------------
__global__ __launch_bounds__(256) void prep_w(const float* __restrict__ W,
                                              u16* __restrict__ Wb) {
    int i = blockIdx.x * 256 + threadIdx.x;
    const float4* p = (const float4*)W;
    float4 v0 = p[(size_t)i * 2], v1 = p[(size_t)i * 2 + 1];
    ((uint4*)Wb)[i] = pack8(v0, v1);
}

// ---------------- gemm + fused score epilogue + fused edge-build ------------
// blocks [0,NEBLK): edge buckets (LDS-local counters, no global atomics);
// blocks [NEBLK, NEBLK+512): 128x128 bf16 MFMA GEMM, A cast from fp32 x.
#define GLDS(g, l)                                                              \
    __builtin_amdgcn_global_load_lds(                                           \
        (const __attribute__((address_space(1))) u32*)(g),                      \
        (__attribute__((address_space(3))) u32*)(l), 16, 0, 0)

__global__ __launch_bounds__(256) void gemm_mfma(
    const float* __restrict__ X, const u16* __restrict__ Bm,
    const float* __restrict__ a, const int* __restrict__ src,
    const int* __restrict__ dst, u16* __restrict__ C, float* __restrict__ s1,
    float* __restrict__ s2, int* __restrict__ cursor,
    int* __restrict__ le_pack, int* __restrict__ csr_dst) {
    __shared__ u16 As[128 * 32];
    __shared__ u16 Bs[128 * 32];
    int tid = threadIdx.x;
    int blk = blockIdx.x;

    if (blk < NEBLK) {
        // ---- edge-bucket build for node range [base, base+128) ----
        int base = blk * 128;
        int* cnt = (int*)As;        // 128 ints
        int* lastp = cnt + 128;     // 128 ints, packed (e<<13)|dst
        if (tid < 128) { cnt[tid] = 0; lastp[tid] = -1; }
        __syncthreads();
        for (int c = 0; c < EDGES; c += 256) {
            int e = c + tid;
            int s = src[e];
            unsigned r = (unsigned)(s - base);
            if (r < 128u) {
                int d = dst[e];
                int slot = atomicAdd(&cnt[r], 1);
                if (slot < CAP) csr_dst[(size_t)s * CAP + slot] = d;
                atomicMax(&lastp[r], (e << 13) | d);
            }
        }
        __syncthreads();
        if (tid < 128) {
            cursor[base + tid] = cnt[tid];
            le_pack[base + tid] = lastp[tid];
        }
        return;
    }

    int gb = blk - NEBLK;
    int m0 = (gb >> 2) * 128, n0 = (gb & 3) * 128;
    int lane = tid & 63, wv = tid >> 6;
    int wr = (wv >> 1) * 64, wc = (wv & 1) * 64;
    int l15 = lane & 15, quad = lane >> 4;
    f32x4 acc[4][4] = {};

    float a1v[4], a2v[4];
#pragma unroll
    for (int j = 0; j < 4; j++) {
        a1v[j] = a[j * 16 + l15];
        a2v[j] = a[DDIM + j * 16 + l15];
    }

    int srow = tid >> 2;         // 0..63
    int scol = (tid & 3) * 8;    // k-offset 0/8/16/24
    const float* Ag = X + (size_t)(m0 + srow) * FIN + scol;
    const u16* Bg = Bm + (size_t)(n0 + srow) * FIN + scol;
    u16* Al = As + tid * 8;
    u16* Bl = Bs + tid * 8;

    for (int k0 = 0; k0 < FIN; k0 += 32) {
        __syncthreads();
        GLDS(Bg + k0, Bl);
        GLDS(Bg + k0 + (size_t)64 * FIN, Bl + 64 * 32);
        float4 fa0 = *(const float4*)(Ag + k0);
        float4 fa1 = *(const float4*)(Ag + k0 + 4);
        float4 fb0 = *(const float4*)(Ag + k0 + (size_t)64 * FIN);
        float4 fb1 = *(const float4*)(Ag + k0 + (size_t)64 * FIN + 4);
        *(uint4*)Al = pack8(fa0, fa1);
        *(uint4*)(Al + 64 * 32) = pack8(fb0, fb1);
        __syncthreads();
        bf16x8 af[4], bfr[4];
#pragma unroll
        for (int i = 0; i < 4; i++)
            af[i] = *(const bf16x8*)(As + (wr + i * 16 + l15) * 32 + quad * 8);
#pragma unroll
        for (int j = 0; j < 4; j++)
            bfr[j] = *(const bf16x8*)(Bs + (wc + j * 16 + l15) * 32 + quad * 8);
#pragma unroll
        for (int i = 0; i < 4; i++)
#pragma unroll
            for (int j = 0; j < 4; j++)
                acc[i][j] = __builtin_amdgcn_mfma_f32_16x16x32_bf16(
                    af[i], bfr[j], acc[i][j], 0, 0, 0);
    }

    // h store (bf16)
#pragma unroll
    for (int i = 0; i < 4; i++) {
        int row_base = m0 + wr + i * 16 + quad * 4;
#pragma unroll
        for (int j = 0; j < 4; j++) {
            int col = n0 + wc + j * 16 + l15;
#pragma unroll
            for (int r = 0; r < 4; r++)
                C[(size_t)(row_base + r) * FOUT + col] = f2bf(acc[i][j][r]);
        }
    }

    // fused score: this wave's 64 cols == exactly one head
    int head = (gb & 3) * 2 + (wv & 1);
#pragma unroll
    for (int i = 0; i < 4; i++) {
#pragma unroll
        for (int r = 0; r < 4; r++) {
            float p1 = 0.f, p2 = 0.f;
#pragma unroll
            for (int j = 0; j < 4; j++) {
                p1 += a1v[j] * acc[i][j][r];
                p2 += a2v[j] * acc[i][j][r];
            }
#pragma unroll
            for (int m = 1; m <= 8; m <<= 1) {
                p1 += __shfl_xor(p1, m);
                p2 += __shfl_xor(p2, m);
            }
            if (l15 == 0) {
                int row = m0 + wr + i * 16 + quad * 4 + r;
                s1[row * H_HEADS + head] = p1;
                s2[row * H_HEADS + head] = p2;
            }
        }
    }
}

// ---------------- aggregate + fused softmax weights ------------------------
// 2 nodes/block; wave = (node, batch); lane: head=l>>3, d=(l&7)*8..+8.
__global__ __launch_bounds__(256) void aggregate(const u16* __restrict__ h,
                                                 const float* __restrict__ s1,
                                                 const float* __restrict__ s2,
                                                 const int* __restrict__ cursor,
                                                 const int* __restrict__ le_pack,
                                                 const int* __restrict__ csr_dst,
                                                 float* __restrict__ out, int N) {
    int n = blockIdx.x * 2 + (threadIdx.x >> 7);
    int b = (threadIdx.x >> 6) & 1;
    int lane = threadIdx.x & 63;
    int head = lane >> 3;

    int deg = cursor[n];
    deg = deg < CAP ? deg : CAP;
    int pk = le_pack[n];

    // cooperative index fetch: lanes 0..31 hold this node's bucket
    const int* cp = csr_dst + (size_t)n * CAP;
    int myidx = (lane < CAP) ? cp[lane] : 0;

    float wgt = 0.f;
    if (pk >= 0) {
        int dl = pk & 8191;
        float sc0 = s1[(0 * N + n) * H_HEADS + head] +
                    s2[((size_t)0 * N + dl) * H_HEADS + head];
        float sc1 = s1[((size_t)1 * N + n) * H_HEADS + head] +
                    s2[((size_t)1 * N + dl) * H_HEADS + head];
        sc0 = sc0 >= 0.f ? sc0 : 0.2f * sc0;
        sc1 = sc1 >= 0.f ? sc1 : 0.2f * sc1;
        float m = fmaxf(sc0, sc1);
        float e0 = __expf(sc0 - m), e1 = __expf(sc1 - m);
        wgt = (b == 0 ? e0 : e1) / (e0 + e1);
    }

    float acc[8] = {};
    const u16* hb = h + (size_t)b * N * FOUT + lane * 8;
    for (int j0 = 0; j0 < deg; j0 += 4) {
#pragma unroll
        for (int k = 0; k < 4; k++) {
            int j = j0 + k;
            float f = (j < deg) ? 1.0f : 0.0f;     // wave-uniform
            int dn = (j < deg) ? __shfl(myidx, j) : 0;
            uint4 v = *(const uint4*)(hb + (size_t)dn * FOUT);
            acc[0] = fmaf(f, bf2f(v.x & 0xffffu), acc[0]);
            acc[1] = fmaf(f, bf2f(v.x >> 16), acc[1]);
            acc[2] = fmaf(f, bf2f(v.y & 0xffffu), acc[2]);
            acc[3] = fmaf(f, bf2f(v.y >> 16), acc[3]);
            acc[4] = fmaf(f, bf2f(v.z & 0xffffu), acc[4]);
            acc[5] = fmaf(f, bf2f(v.z >> 16), acc[5]);
            acc[6] = fmaf(f, bf2f(v.w & 0xffffu), acc[6]);
            acc[7] = fmaf(f, bf2f(v.w >> 16), acc[7]);
        }
    }
    float val[8];
#pragma unroll
    for (int k = 0; k < 8; k++) val[k] = acc[k] * wgt;
#pragma unroll
    for (int m = 8; m <= 32; m <<= 1)
#pragma unroll
        for (int k = 0; k < 8; k++) val[k] += __shfl_xor(val[k], m);
    if (lane < 8) {
        float* op = out + ((size_t)b * N + n) * DDIM + lane * 8;
        const float inv = 1.0f / H_HEADS;
        *(float4*)op = make_float4(val[0] * inv, val[1] * inv, val[2] * inv,
                                   val[3] * inv);
        *(float4*)(op + 4) = make_float4(val[4] * inv, val[5] * inv,
                                         val[6] * inv, val[7] * inv);
    }
}

// ---------------------------------------------------------------------------
extern "C" void kernel_launch(void* const* d_in, const int* in_sizes, int n_in,
                              void* d_out, int out_size, void* d_ws,
                              size_t ws_size, hipStream_t stream) {
    const float* x = (const float*)d_in[0];
    const int* edges = (const int*)d_in[1];
    const float* W = (const float*)d_in[2];
    const float* a = (const float*)d_in[3];
    float* out = (float*)d_out;

    const int* src = edges;
    const int* dst = edges + EDGES;

    char* p = (char*)d_ws;
    auto carve = [&](size_t bytes) {
        char* r = p;
        p += (bytes + 255) & ~(size_t)255;
        return r;
    };
    u16* Wb = (u16*)carve((size_t)FOUT * FIN * 2);
    u16* h = (u16*)carve((size_t)BB * NNODES * FOUT * 2);
    float* s1 = (float*)carve((size_t)BB * NNODES * H_HEADS * 4);
    float* s2 = (float*)carve((size_t)BB * NNODES * H_HEADS * 4);
    int* cursor = (int*)carve(NNODES * 4);
    int* le_pack = (int*)carve(NNODES * 4);
    int* csr_dst = (int*)carve((size_t)NNODES * CAP * 4);

    const int M = BB * NNODES;

    // W cast (gemm blocks need Wb via GLDS; edge blocks don't touch it)
    prep_w<<<FOUT * FIN / 8 / 256, 256, 0, stream>>>(W, Wb);
    // fused: 64 edge-build blocks (first) + 512 GEMM blocks
    gemm_mfma<<<NEBLK + (M / 128) * (FOUT / 128), 256, 0, stream>>>(
        x, Wb, a, src, dst, h, s1, s2, cursor, le_pack, csr_dst);
    aggregate<<<NNODES / 2, 256, 0, stream>>>(h, s1, s2, cursor, le_pack,
                                              csr_dst, out, NNODES);
}

// Round 7
// 124.978 us; speedup vs baseline: 1.5657x; 1.5657x over previous
//
#include <hip/hip_runtime.h>
#include <stdint.h>

#define H_HEADS 8
#define DDIM 64
#define NNODES 8192
#define BB 2
#define FIN 512
#define FOUT 512
#define EDGES 65536
#define CAP 32   // per-node edge bucket capacity (Poisson λ=8; P(deg>=32)~1e-11)

typedef unsigned short u16;
typedef unsigned int u32;
typedef __bf16 bf16x8 __attribute__((ext_vector_type(8)));
typedef float f32x4 __attribute__((ext_vector_type(4)));

__device__ __forceinline__ u16 f2bf(float f) {
    u32 u = __float_as_uint(f);
    return (u16)((u + 0x7FFFu + ((u >> 16) & 1u)) >> 16);
}
__device__ __forceinline__ float bf2f(u32 s) {
    return __uint_as_float(s << 16);
}
__device__ __forceinline__ uint4 pack8(float4 a, float4 b) {
    return make_uint4(f2bf(a.x) | ((u32)f2bf(a.y) << 16),
                      f2bf(a.z) | ((u32)f2bf(a.w) << 16),
                      f2bf(b.x) | ((u32)f2bf(b.y) << 16),
                      f2bf(b.z) | ((u32)f2bf(b.w) << 16));
}

// ---------------- prep: cast W -> bf16  +  edge bucket build ----------------
// (round-5 shape: high-parallelism edge build via global atomics)
#define NWB (FOUT * FIN / 8 / 256)          // 128 blocks
#define NEB 64                              // 64 blocks * 256 thr * 4 edges
__global__ __launch_bounds__(256) void prep_kernel(
    const float* __restrict__ W, const int* __restrict__ src,
    const int* __restrict__ dst, u16* __restrict__ Wb,
    int* __restrict__ cursor, int* __restrict__ le_pack,
    int* __restrict__ csr_dst) {
    int blk = blockIdx.x;
    if (blk < NWB) {
        int i = blk * 256 + threadIdx.x;
        const float4* p = (const float4*)W;
        float4 v0 = p[(size_t)i * 2], v1 = p[(size_t)i * 2 + 1];
        ((uint4*)Wb)[i] = pack8(v0, v1);
    } else {
        int t = (blk - NWB) * 256 + threadIdx.x;  // 0..16383
#pragma unroll
        for (int k = 0; k < 4; k++) {
            int e = t * 4 + k;
            int s = src[e], d = dst[e];
            int slot = atomicAdd(&cursor[s], 1);
            if (slot < CAP) csr_dst[(size_t)s * CAP + slot] = d;
            // packed argmax-by-e; all packs >= 0 so memset-0 init is safe
            // (pk only consumed when deg>0)
            atomicMax(&le_pack[s], (e << 13) | d);
        }
    }
}

// ---------------- bf16 MFMA GEMM (A from fp32 x, in-kernel cvt) -------------
// C[m][n] = sum_k A[m][k]*B[n][k]; also s1[m,h]=C[m,:]·a1, s2=·a2 per head.
#define GLDS(g, l)                                                              \
    __builtin_amdgcn_global_load_lds(                                           \
        (const __attribute__((address_space(1))) u32*)(g),                      \
        (__attribute__((address_space(3))) u32*)(l), 16, 0, 0)

__global__ __launch_bounds__(256) void gemm_mfma(const float* __restrict__ X,
                                                 const u16* __restrict__ Bm,
                                                 const float* __restrict__ a,
                                                 u16* __restrict__ C,
                                                 float* __restrict__ s1,
                                                 float* __restrict__ s2) {
    __shared__ u16 As[128 * 32];
    __shared__ u16 Bs[128 * 32];
    int tid = threadIdx.x;
    // XCD swizzle: the 4 n-blocks sharing one A-tile get blockIdx values
    // {b, b+8, b+16, b+24} -> same XCD (blk%8) -> A re-reads hit that XCD's L2.
    int gb = blockIdx.x;
    int m_idx = (gb & 7) | ((gb >> 5) << 3);   // 0..127
    int n_idx = (gb >> 3) & 3;                 // 0..3
    int m0 = m_idx * 128, n0 = n_idx * 128;
    int lane = tid & 63, wv = tid >> 6;
    int wr = (wv >> 1) * 64, wc = (wv & 1) * 64;
    int l15 = lane & 15, quad = lane >> 4;
    f32x4 acc[4][4] = {};

    float a1v[4], a2v[4];
#pragma unroll
    for (int j = 0; j < 4; j++) {
        a1v[j] = a[j * 16 + l15];
        a2v[j] = a[DDIM + j * 16 + l15];
    }

    int srow = tid >> 2;         // 0..63
    int scol = (tid & 3) * 8;    // k-offset 0/8/16/24
    const float* Ag = X + (size_t)(m0 + srow) * FIN + scol;
    const u16* Bg = Bm + (size_t)(n0 + srow) * FIN + scol;
    u16* Al = As + tid * 8;
    u16* Bl = Bs + tid * 8;

    for (int k0 = 0; k0 < FIN; k0 += 32) {
        __syncthreads();
        GLDS(Bg + k0, Bl);
        GLDS(Bg + k0 + (size_t)64 * FIN, Bl + 64 * 32);
        float4 fa0 = *(const float4*)(Ag + k0);
        float4 fa1 = *(const float4*)(Ag + k0 + 4);
        float4 fb0 = *(const float4*)(Ag + k0 + (size_t)64 * FIN);
        float4 fb1 = *(const float4*)(Ag + k0 + (size_t)64 * FIN + 4);
        *(uint4*)Al = pack8(fa0, fa1);
        *(uint4*)(Al + 64 * 32) = pack8(fb0, fb1);
        __syncthreads();
        bf16x8 af[4], bfr[4];
#pragma unroll
        for (int i = 0; i < 4; i++)
            af[i] = *(const bf16x8*)(As + (wr + i * 16 + l15) * 32 + quad * 8);
#pragma unroll
        for (int j = 0; j < 4; j++)
            bfr[j] = *(const bf16x8*)(Bs + (wc + j * 16 + l15) * 32 + quad * 8);
#pragma unroll
        for (int i = 0; i < 4; i++)
#pragma unroll
            for (int j = 0; j < 4; j++)
                acc[i][j] = __builtin_amdgcn_mfma_f32_16x16x32_bf16(
                    af[i], bfr[j], acc[i][j], 0, 0, 0);
    }

    // h store (bf16)
#pragma unroll
    for (int i = 0; i < 4; i++) {
        int row_base = m0 + wr + i * 16 + quad * 4;
#pragma unroll
        for (int j = 0; j < 4; j++) {
            int col = n0 + wc + j * 16 + l15;
#pragma unroll
            for (int r = 0; r < 4; r++)
                C[(size_t)(row_base + r) * FOUT + col] = f2bf(acc[i][j][r]);
        }
    }

    // fused score: this wave's 64 cols == exactly one head
    int head = n_idx * 2 + (wv & 1);
#pragma unroll
    for (int i = 0; i < 4; i++) {
#pragma unroll
        for (int r = 0; r < 4; r++) {
            float p1 = 0.f, p2 = 0.f;
#pragma unroll
            for (int j = 0; j < 4; j++) {
                p1 += a1v[j] * acc[i][j][r];
                p2 += a2v[j] * acc[i][j][r];
            }
#pragma unroll
            for (int m = 1; m <= 8; m <<= 1) {
                p1 += __shfl_xor(p1, m);
                p2 += __shfl_xor(p2, m);
            }
            if (l15 == 0) {
                int row = m0 + wr + i * 16 + quad * 4 + r;
                s1[row * H_HEADS + head] = p1;
                s2[row * H_HEADS + head] = p2;
            }
        }
    }
}

// ---------------- aggregate + fused softmax weights ------------------------
// 2 nodes/block; wave = (node, batch); lane: head=l>>3, d=(l&7)*8..+8.
__global__ __launch_bounds__(256) void aggregate(const u16* __restrict__ h,
                                                 const float* __restrict__ s1,
                                                 const float* __restrict__ s2,
                                                 const int* __restrict__ cursor,
                                                 const int* __restrict__ le_pack,
                                                 const int* __restrict__ csr_dst,
                                                 float* __restrict__ out, int N) {
    int n = blockIdx.x * 2 + (threadIdx.x >> 7);
    int b = (threadIdx.x >> 6) & 1;
    int lane = threadIdx.x & 63;
    int head = lane >> 3;

    int deg = cursor[n];
    deg = deg < CAP ? deg : CAP;
    int pk = le_pack[n];

    // cooperative index fetch: lanes 0..31 hold this node's bucket
    const int* cp = csr_dst + (size_t)n * CAP;
    int myidx = (lane < CAP) ? cp[lane] : 0;

    float wgt = 0.f;
    if (deg > 0) {
        int dl = pk & 8191;
        float sc0 = s1[(0 * N + n) * H_HEADS + head] +
                    s2[((size_t)0 * N + dl) * H_HEADS + head];
        float sc1 = s1[((size_t)1 * N + n) * H_HEADS + head] +
                    s2[((size_t)1 * N + dl) * H_HEADS + head];
        sc0 = sc0 >= 0.f ? sc0 : 0.2f * sc0;
        sc1 = sc1 >= 0.f ? sc1 : 0.2f * sc1;
        float m = fmaxf(sc0, sc1);
        float e0 = __expf(sc0 - m), e1 = __expf(sc1 - m);
        wgt = (b == 0 ? e0 : e1) / (e0 + e1);
    }

    float acc[8] = {};
    const u16* hb = h + (size_t)b * N * FOUT + lane * 8;
    for (int j0 = 0; j0 < deg; j0 += 4) {
#pragma unroll
        for (int k = 0; k < 4; k++) {
            int j = j0 + k;
            float f = (j < deg) ? 1.0f : 0.0f;     // wave-uniform
            int dn = (j < deg) ? __shfl(myidx, j) : 0;
            uint4 v = *(const uint4*)(hb + (size_t)dn * FOUT);
            acc[0] = fmaf(f, bf2f(v.x & 0xffffu), acc[0]);
            acc[1] = fmaf(f, bf2f(v.x >> 16), acc[1]);
            acc[2] = fmaf(f, bf2f(v.y & 0xffffu), acc[2]);
            acc[3] = fmaf(f, bf2f(v.y >> 16), acc[3]);
            acc[4] = fmaf(f, bf2f(v.z & 0xffffu), acc[4]);
            acc[5] = fmaf(f, bf2f(v.z >> 16), acc[5]);
            acc[6] = fmaf(f, bf2f(v.w & 0xffffu), acc[6]);
            acc[7] = fmaf(f, bf2f(v.w >> 16), acc[7]);
        }
    }
    float val[8];
#pragma unroll
    for (int k = 0; k < 8; k++) val[k] = acc[k] * wgt;
#pragma unroll
    for (int m = 8; m <= 32; m <<= 1)
#pragma unroll
        for (int k = 0; k < 8; k++) val[k] += __shfl_xor(val[k], m);
    if (lane < 8) {
        float* op = out + ((size_t)b * N + n) * DDIM + lane * 8;
        const float inv = 1.0f / H_HEADS;
        *(float4*)op = make_float4(val[0] * inv, val[1] * inv, val[2] * inv,
                                   val[3] * inv);
        *(float4*)(op + 4) = make_float4(val[4] * inv, val[5] * inv,
                                         val[6] * inv, val[7] * inv);
    }
}

// ---------------------------------------------------------------------------
extern "C" void kernel_launch(void* const* d_in, const int* in_sizes, int n_in,
                              void* d_out, int out_size, void* d_ws,
                              size_t ws_size, hipStream_t stream) {
    const float* x = (const float*)d_in[0];
    const int* edges = (const int*)d_in[1];
    const float* W = (const float*)d_in[2];
    const float* a = (const float*)d_in[3];
    float* out = (float*)d_out;

    const int* src = edges;
    const int* dst = edges + EDGES;

    char* p = (char*)d_ws;
    auto carve = [&](size_t bytes) {
        char* r = p;
        p += (bytes + 255) & ~(size_t)255;
        return r;
    };
    u16* Wb = (u16*)carve((size_t)FOUT * FIN * 2);
    u16* h = (u16*)carve((size_t)BB * NNODES * FOUT * 2);
    float* s1 = (float*)carve((size_t)BB * NNODES * H_HEADS * 4);
    float* s2 = (float*)carve((size_t)BB * NNODES * H_HEADS * 4);
    int* cursor = (int*)carve(NNODES * 4);       // adjacent: one memset
    int* le_pack = (int*)carve(NNODES * 4);
    int* csr_dst = (int*)carve((size_t)NNODES * CAP * 4);

    const int M = BB * NNODES;

    // zero cursor + le_pack (adjacent 64 KB); all le packs >= 0 and pk is
    // only consumed when deg>0, so 0-init is safe.
    hipMemsetAsync(cursor, 0, 2 * NNODES * 4, stream);
    prep_kernel<<<NWB + NEB, 256, 0, stream>>>(W, src, dst, Wb, cursor,
                                               le_pack, csr_dst);
    gemm_mfma<<<(M / 128) * (FOUT / 128), 256, 0, stream>>>(x, Wb, a, h, s1,
                                                            s2);
    aggregate<<<NNODES / 2, 256, 0, stream>>>(h, s1, s2, cursor, le_pack,
                                              csr_dst, out, NNODES);
}